// Round 3
// baseline (552.031 us; speedup 1.0000x reference)
//
#include <hip/hip_runtime.h>
#include <hip/hip_bf16.h>

#define NB   2
#define NH   8
#define NSEQ 4096
#define DKH  64
#define HD   512

typedef unsigned short u16;
typedef unsigned int   u32;
typedef short s16x8 __attribute__((ext_vector_type(8)));
typedef u16   u16x8 __attribute__((ext_vector_type(8)));
typedef u16   u16x4 __attribute__((ext_vector_type(4)));
typedef float f32x4 __attribute__((ext_vector_type(4)));

#define L2E 1.4426950408889634f

static __device__ __forceinline__ u16 f2bf(float f) {
    u32 u = __builtin_bit_cast(u32, f);
    u32 r = (u + 0x7fffu + ((u >> 16) & 1u)) >> 16;
    return (u16)r;
}
static __device__ __forceinline__ float bf2f(u16 h) {
    return __builtin_bit_cast(float, (u32)h << 16);
}
static __device__ __forceinline__ f32x4 mm16(s16x8 a, s16x8 b, f32x4 c) {
    return __builtin_amdgcn_mfma_f32_16x16x32_bf16(a, b, c, 0, 0, 0);
}
static __device__ __forceinline__ s16x8 ld8(const u16* p) {
    return __builtin_bit_cast(s16x8, *(const u16x8*)p);
}
// Raw barrier: LDS-only ordering, does NOT drain vmcnt (keeps global stores
// and prefetch loads in flight across the barrier). rule #18: sched_barrier
// fences around the inline-asm waitcnt.
static __device__ __forceinline__ void bar_sync() {
    __builtin_amdgcn_sched_barrier(0);
    asm volatile("s_waitcnt lgkmcnt(0)" ::: "memory");
    __builtin_amdgcn_sched_barrier(0);
    __builtin_amdgcn_s_barrier();
    __builtin_amdgcn_sched_barrier(0);
}

// ---------------------------------------------------------------------------
// Kernel A: Y = X @ W^T + bias, split-bf16 output.  (unchanged)
// ---------------------------------------------------------------------------
template<int TERMS, int MODE>
__launch_bounds__(256, 2)
__global__ void proj_kernel(const float* __restrict__ X, const float* __restrict__ W,
                            const float* __restrict__ bias,
                            u16* __restrict__ Yhi, u16* __restrict__ Ylo, float scale)
{
    __shared__ u16 xh[128][40], xl[128][40], wh[128][40], wl[128][40];
    const int t = threadIdx.x;
    const int lane = t & 63, wave = t >> 6;
    const int lg = lane >> 4, lr = lane & 15;
    const int wr = (wave >> 1) * 64, wc = (wave & 1) * 64;
    const int m0 = blockIdx.x * 128, n0 = blockIdx.y * 128;

    f32x4 acc[4][4] = {};

    for (int k0 = 0; k0 < HD; k0 += 32) {
        #pragma unroll
        for (int i = 0; i < 4; i++) {
            int idx = t + i * 256;
            int r = idx >> 3, c = (idx & 7) * 4;
            float4 v = *(const float4*)(X + (size_t)(m0 + r) * HD + k0 + c);
            u16 h0 = f2bf(v.x), h1 = f2bf(v.y), h2 = f2bf(v.z), h3 = f2bf(v.w);
            u16x4 hv; hv[0] = h0; hv[1] = h1; hv[2] = h2; hv[3] = h3;
            *(u16x4*)&xh[r][c] = hv;
            if (TERMS >= 2) {
                u16x4 lv;
                lv[0] = f2bf(v.x - bf2f(h0)); lv[1] = f2bf(v.y - bf2f(h1));
                lv[2] = f2bf(v.z - bf2f(h2)); lv[3] = f2bf(v.w - bf2f(h3));
                *(u16x4*)&xl[r][c] = lv;
            }
            float4 w = *(const float4*)(W + (size_t)(n0 + r) * HD + k0 + c);
            u16 g0 = f2bf(w.x), g1 = f2bf(w.y), g2 = f2bf(w.z), g3 = f2bf(w.w);
            u16x4 gv; gv[0] = g0; gv[1] = g1; gv[2] = g2; gv[3] = g3;
            *(u16x4*)&wh[r][c] = gv;
            if (TERMS >= 3) {
                u16x4 lv;
                lv[0] = f2bf(w.x - bf2f(g0)); lv[1] = f2bf(w.y - bf2f(g1));
                lv[2] = f2bf(w.z - bf2f(g2)); lv[3] = f2bf(w.w - bf2f(g3));
                *(u16x4*)&wl[r][c] = lv;
            }
        }
        __syncthreads();
        const int kk = lg * 8;
        s16x8 ah[4], al[4], bh[4], bl[4];
        #pragma unroll
        for (int f = 0; f < 4; f++) {
            ah[f] = ld8(&xh[wr + f * 16 + lr][kk]);
            if (TERMS >= 2) al[f] = ld8(&xl[wr + f * 16 + lr][kk]);
            bh[f] = ld8(&wh[wc + f * 16 + lr][kk]);
            if (TERMS >= 3) bl[f] = ld8(&wl[wc + f * 16 + lr][kk]);
        }
        #pragma unroll
        for (int m = 0; m < 4; m++)
            #pragma unroll
            for (int n = 0; n < 4; n++) {
                acc[m][n] = mm16(ah[m], bh[n], acc[m][n]);
                if (TERMS >= 2) acc[m][n] = mm16(al[m], bh[n], acc[m][n]);
                if (TERMS >= 3) acc[m][n] = mm16(ah[m], bl[n], acc[m][n]);
            }
        __syncthreads();
    }

    float bv[4];
    #pragma unroll
    for (int n = 0; n < 4; n++) bv[n] = bias[n0 + wc + n * 16 + lr];

    #pragma unroll
    for (int m = 0; m < 4; m++)
        #pragma unroll
        for (int n = 0; n < 4; n++) {
            int col = n0 + wc + n * 16 + lr;
            int h = col >> 6, d = col & 63;
            #pragma unroll
            for (int j = 0; j < 4; j++) {
                int row = m0 + wr + m * 16 + lg * 4 + j;
                int b = row >> 12, nn = row & (NSEQ - 1);
                float y = (acc[m][n][j] + bv[n]) * scale;
                u16 hi = f2bf(y);
                if (MODE == 0) {
                    size_t o = (((size_t)(b * NH + h) * NSEQ) + nn) * DKH + d;
                    Yhi[o] = hi;
                    Ylo[o] = f2bf(y - bf2f(hi));
                } else {
                    size_t o = ((size_t)(b * NH + h) * DKH + d) * (size_t)NSEQ + nn;
                    Yhi[o] = hi;
                }
            }
        }
}

// ---------------------------------------------------------------------------
// XCD-aware swizzle: each XCD owns bh pair {2r, 2r+1} -> K/V L2-resident.
// ---------------------------------------------------------------------------
static __device__ __forceinline__ void swz_bh_q(int& bh, int& qblk) {
    int f = blockIdx.x + 32 * blockIdx.y;
    int r = f & 7, q = f >> 3;
    bh = 2 * r + (q >> 5);
    qblk = q & 31;
}

// ---------------------------------------------------------------------------
// Kernel C (fused): phase 1 = rowsum (1-term scores, exp-sum over K),
// phase 2 = 3-term scores, attn = exp(s)/l nontemporal f32 store, fused PV.
// All barriers are lgkm-only (stores stay in flight).
// ---------------------------------------------------------------------------
#define NT (NSEQ / 64)

__launch_bounds__(256, 2)
__global__ void attn_kernel(const u16* __restrict__ Qh, const u16* __restrict__ Ql,
                            const u16* __restrict__ Kh, const u16* __restrict__ Kl,
                            const u16* __restrict__ Vt,
                            float* __restrict__ attn, u16* __restrict__ ctx)
{
    __shared__ u16 kh[2][64][72], kl[2][64][72], vt[2][64][72];
    __shared__ u16 plds[4][32][72];
    const int t = threadIdx.x, lane = t & 63, wave = t >> 6;
    const int lg = lane >> 4, lr = lane & 15;
    int bh, qblk; swz_bh_q(bh, qblk);
    const int q0 = qblk * 128 + wave * 32;
    const size_t nbase = (size_t)bh * NSEQ;

    // staging geometry: each thread covers rows (sr, sr+32) x 8 cols
    const int sr = t >> 3;
    const int sc = (t & 7) * 8;
    const u16* gK  = Kh + nbase * DKH + (size_t)sr * DKH + sc;
    const u16* gKl = Kl + nbase * DKH + (size_t)sr * DKH + sc;
    const u16* gV  = Vt + ((size_t)bh * DKH + sr) * NSEQ + sc;

    s16x8 qh[2][2], ql[2][2];
    #pragma unroll
    for (int qi = 0; qi < 2; qi++)
        #pragma unroll
        for (int ds = 0; ds < 2; ds++) {
            size_t o = (nbase + q0 + qi * 16 + lr) * DKH + ds * 32 + lg * 8;
            qh[qi][ds] = ld8(Qh + o);
            ql[qi][ds] = ld8(Ql + o);
        }

    // ================= phase 1: l[row] = sum_k exp(s1) =================
    float sums[2][4] = {};
    {
        *(u16x8*)&kh[0][sr][sc]      = *(const u16x8*)(gK);
        *(u16x8*)&kh[0][sr + 32][sc] = *(const u16x8*)(gK + (size_t)32 * DKH);
        bar_sync();
        for (int tt = 0; tt < NT; tt++) {
            const int cur = tt & 1, nxt = cur ^ 1;
            u16x8 pk0, pk1;
            if (tt + 1 < NT) {
                pk0 = *(const u16x8*)(gK + (size_t)(tt * 64 + 64) * DKH);
                pk1 = *(const u16x8*)(gK + (size_t)(tt * 64 + 96) * DKH);
            }
            f32x4 S[2][4] = {};
            __builtin_amdgcn_s_setprio(1);
            #pragma unroll
            for (int ds = 0; ds < 2; ds++) {
                s16x8 bf[4];
                #pragma unroll
                for (int kf = 0; kf < 4; kf++)
                    bf[kf] = ld8(&kh[cur][kf * 16 + lr][ds * 32 + lg * 8]);
                #pragma unroll
                for (int qi = 0; qi < 2; qi++)
                    #pragma unroll
                    for (int kf = 0; kf < 4; kf++)
                        S[qi][kf] = mm16(qh[qi][ds], bf[kf], S[qi][kf]);
            }
            __builtin_amdgcn_s_setprio(0);
            #pragma unroll
            for (int qi = 0; qi < 2; qi++)
                #pragma unroll
                for (int kf = 0; kf < 4; kf++)
                    #pragma unroll
                    for (int j = 0; j < 4; j++)
                        sums[qi][j] += __builtin_amdgcn_exp2f(S[qi][kf][j] * L2E);
            if (tt + 1 < NT) {
                *(u16x8*)&kh[nxt][sr][sc]      = pk0;
                *(u16x8*)&kh[nxt][sr + 32][sc] = pk1;
            }
            bar_sync();
        }
    }
    #pragma unroll
    for (int m = 1; m < 16; m <<= 1)
        #pragma unroll
        for (int qi = 0; qi < 2; qi++)
            #pragma unroll
            for (int j = 0; j < 4; j++)
                sums[qi][j] += __shfl_xor(sums[qi][j], m, 64);

    float lrl[2][4];
    size_t arow[2][4];
    #pragma unroll
    for (int qi = 0; qi < 2; qi++)
        #pragma unroll
        for (int j = 0; j < 4; j++) {
            int row = q0 + qi * 16 + lg * 4 + j;
            lrl[qi][j] = -__builtin_amdgcn_logf(sums[qi][j]);   // -log2(l)
            arow[qi][j] = (nbase + row) * (size_t)NSEQ + lr;
        }

    // ================= phase 2: attn + PV =================
    #pragma unroll
    for (int i = 0; i < 2; i++) {
        int r = sr + i * 32;
        *(u16x8*)&kh[0][r][sc] = *(const u16x8*)(gK  + (size_t)(i * 32) * DKH);
        *(u16x8*)&kl[0][r][sc] = *(const u16x8*)(gKl + (size_t)(i * 32) * DKH);
        *(u16x8*)&vt[0][r][sc] = *(const u16x8*)(gV  + (size_t)(i * 32) * NSEQ);
    }
    bar_sync();

    f32x4 O[2][4] = {};
    for (int tt = 0; tt < NT; tt++) {
        const int cur = tt & 1, nxt = cur ^ 1;
        const int k0 = tt * 64;

        u16x8 pk[2], pkl[2], pv[2];
        if (tt + 1 < NT) {
            #pragma unroll
            for (int i = 0; i < 2; i++) {
                size_t ko = (size_t)(k0 + 64 + i * 32);
                pk[i]  = *(const u16x8*)(gK  + ko * DKH);
                pkl[i] = *(const u16x8*)(gKl + ko * DKH);
                pv[i]  = *(const u16x8*)(gV  + (size_t)(i * 32) * NSEQ + k0 + 64);
            }
        }

        f32x4 S[2][4] = {};
        __builtin_amdgcn_s_setprio(1);
        #pragma unroll
        for (int ds = 0; ds < 2; ds++) {
            s16x8 bkh[4], bkl[4];
            #pragma unroll
            for (int kf = 0; kf < 4; kf++) {
                bkh[kf] = ld8(&kh[cur][kf * 16 + lr][ds * 32 + lg * 8]);
                bkl[kf] = ld8(&kl[cur][kf * 16 + lr][ds * 32 + lg * 8]);
            }
            #pragma unroll
            for (int qi = 0; qi < 2; qi++)
                #pragma unroll
                for (int kf = 0; kf < 4; kf++) {
                    S[qi][kf] = mm16(qh[qi][ds], bkh[kf], S[qi][kf]);
                    S[qi][kf] = mm16(ql[qi][ds], bkh[kf], S[qi][kf]);
                    S[qi][kf] = mm16(qh[qi][ds], bkl[kf], S[qi][kf]);
                }
        }
        __builtin_amdgcn_s_setprio(0);

        #pragma unroll
        for (int qi = 0; qi < 2; qi++)
            #pragma unroll
            for (int kf = 0; kf < 4; kf++)
                #pragma unroll
                for (int j = 0; j < 4; j++) {
                    float p = __builtin_amdgcn_exp2f(fmaf(S[qi][kf][j], L2E, lrl[qi][j]));
                    __builtin_nontemporal_store(p, &attn[arow[qi][j] + k0 + kf * 16]);
                    plds[wave][qi * 16 + lg * 4 + j][kf * 16 + lr] = f2bf(p);
                }

        __builtin_amdgcn_wave_barrier();   // plds is wave-private

        __builtin_amdgcn_s_setprio(1);
        #pragma unroll
        for (int ks = 0; ks < 2; ks++) {
            s16x8 pa[2], vb[4];
            #pragma unroll
            for (int qi = 0; qi < 2; qi++)
                pa[qi] = ld8(&plds[wave][qi * 16 + lr][ks * 32 + lg * 8]);
            #pragma unroll
            for (int df = 0; df < 4; df++)
                vb[df] = ld8(&vt[cur][df * 16 + lr][ks * 32 + lg * 8]);
            #pragma unroll
            for (int qi = 0; qi < 2; qi++)
                #pragma unroll
                for (int df = 0; df < 4; df++)
                    O[qi][df] = mm16(pa[qi], vb[df], O[qi][df]);
        }
        __builtin_amdgcn_s_setprio(0);

        if (tt + 1 < NT) {
            #pragma unroll
            for (int i = 0; i < 2; i++) {
                int r = sr + i * 32;
                *(u16x8*)&kh[nxt][r][sc] = pk[i];
                *(u16x8*)&kl[nxt][r][sc] = pkl[i];
                *(u16x8*)&vt[nxt][r][sc] = pv[i];
            }
        }
        bar_sync();
    }

    const int b = bh >> 3, h = bh & 7;
    #pragma unroll
    for (int qi = 0; qi < 2; qi++)
        #pragma unroll
        for (int df = 0; df < 4; df++)
            #pragma unroll
            for (int j = 0; j < 4; j++) {
                int n = q0 + qi * 16 + lg * 4 + j;
                int col = h * 64 + df * 16 + lr;
                ctx[((size_t)b * NSEQ + n) * HD + col] = f2bf(O[qi][df][j]);
            }
}

// ---------------------------------------------------------------------------
// Kernel D: out = ctx @ Wo^T + bo  (unchanged)
// ---------------------------------------------------------------------------
__launch_bounds__(256, 2)
__global__ void outproj_kernel(const u16* __restrict__ Xc, const float* __restrict__ W,
                               const float* __restrict__ bias, float* __restrict__ out)
{
    __shared__ u16 xh[128][72], wh[128][72];
    const int t = threadIdx.x, lane = t & 63, wave = t >> 6;
    const int lg = lane >> 4, lr = lane & 15;
    const int wr = (wave >> 1) * 64, wc = (wave & 1) * 64;
    const int m0 = blockIdx.x * 128, n0 = blockIdx.y * 128;

    f32x4 acc[4][4] = {};
    for (int k0 = 0; k0 < HD; k0 += 64) {
        #pragma unroll
        for (int i = 0; i < 4; i++) {
            int idx = t + i * 256;
            int r = idx >> 3, c = (idx & 7) * 8;
            *(u16x8*)&xh[r][c] = *(const u16x8*)(Xc + (size_t)(m0 + r) * HD + k0 + c);
        }
        #pragma unroll
        for (int i = 0; i < 8; i++) {
            int idx = t + i * 256;
            int r = idx >> 4, c = (idx & 15) * 4;
            float4 v = *(const float4*)(W + (size_t)(n0 + r) * HD + k0 + c);
            u16x4 gv; gv[0] = f2bf(v.x); gv[1] = f2bf(v.y); gv[2] = f2bf(v.z); gv[3] = f2bf(v.w);
            *(u16x4*)&wh[r][c] = gv;
        }
        __syncthreads();
        #pragma unroll
        for (int ks = 0; ks < 2; ks++) {
            s16x8 af[4], bf[4];
            int kk = ks * 32 + lg * 8;
            #pragma unroll
            for (int f = 0; f < 4; f++) {
                af[f] = ld8(&xh[wr + f * 16 + lr][kk]);
                bf[f] = ld8(&wh[wc + f * 16 + lr][kk]);
            }
            #pragma unroll
            for (int m = 0; m < 4; m++)
                #pragma unroll
                for (int n = 0; n < 4; n++)
                    acc[m][n] = mm16(af[m], bf[n], acc[m][n]);
        }
        __syncthreads();
    }
    #pragma unroll
    for (int m = 0; m < 4; m++)
        #pragma unroll
        for (int n = 0; n < 4; n++) {
            int col = n0 + wc + n * 16 + lr;
            float bv = bias[col];
            #pragma unroll
            for (int j = 0; j < 4; j++) {
                int row = m0 + wr + m * 16 + lg * 4 + j;
                out[(size_t)row * HD + col] = acc[m][n][j] + bv;
            }
        }
}

// ---------------------------------------------------------------------------
extern "C" void kernel_launch(void* const* d_in, const int* in_sizes, int n_in,
                              void* d_out, int out_size, void* d_ws, size_t ws_size,
                              hipStream_t stream)
{
    const float* query = (const float*)d_in[0];
    const float* key   = (const float*)d_in[1];
    const float* value = (const float*)d_in[2];
    const float* Wq = (const float*)d_in[3];
    const float* bq = (const float*)d_in[4];
    const float* Wk = (const float*)d_in[5];
    const float* bk = (const float*)d_in[6];
    const float* Wv = (const float*)d_in[7];
    const float* bv = (const float*)d_in[8];
    const float* Wo = (const float*)d_in[9];
    const float* bo = (const float*)d_in[10];

    float* out  = (float*)d_out;
    float* attn = out + (size_t)NB * NSEQ * HD;

    const size_t E = (size_t)NB * NH * NSEQ * DKH;
    u16* qhi = (u16*)d_ws;
    u16* qlo = qhi + E;
    u16* khi = qlo + E;
    u16* klo = khi + E;
    u16* vt  = klo + E;
    u16* ctx = vt + E;

    dim3 gp(64, 4), bp(256);
    proj_kernel<3, 0><<<gp, bp, 0, stream>>>(query, Wq, bq, qhi, qlo, 0.125f);
    proj_kernel<3, 0><<<gp, bp, 0, stream>>>(key,   Wk, bk, khi, klo, 1.0f);
    proj_kernel<1, 1><<<gp, bp, 0, stream>>>(value, Wv, bv, vt, (u16*)nullptr, 1.0f);
    attn_kernel<<<dim3(32, 16), dim3(256), 0, stream>>>(qhi, qlo, khi, klo, vt, attn, ctx);
    outproj_kernel<<<gp, bp, 0, stream>>>(ctx, Wo, bo, out);
}

// Round 4
// 530.583 us; speedup vs baseline: 1.0404x; 1.0404x over previous
//
#include <hip/hip_runtime.h>
#include <hip/hip_bf16.h>

#define NB   2
#define NH   8
#define NSEQ 4096
#define DKH  64
#define HD   512

typedef unsigned short u16;
typedef unsigned int   u32;
typedef short s16x8 __attribute__((ext_vector_type(8)));
typedef u16   u16x8 __attribute__((ext_vector_type(8)));
typedef u16   u16x4 __attribute__((ext_vector_type(4)));
typedef float f32x4 __attribute__((ext_vector_type(4)));

#define L2E 1.4426950408889634f

static __device__ __forceinline__ u16 f2bf(float f) {
    u32 u = __builtin_bit_cast(u32, f);
    u32 r = (u + 0x7fffu + ((u >> 16) & 1u)) >> 16;
    return (u16)r;
}
static __device__ __forceinline__ float bf2f(u16 h) {
    return __builtin_bit_cast(float, (u32)h << 16);
}
static __device__ __forceinline__ f32x4 mm16(s16x8 a, s16x8 b, f32x4 c) {
    return __builtin_amdgcn_mfma_f32_16x16x32_bf16(a, b, c, 0, 0, 0);
}
static __device__ __forceinline__ s16x8 ld8(const u16* p) {
    return __builtin_bit_cast(s16x8, *(const u16x8*)p);
}
// Raw barrier: LDS-only ordering, does NOT drain vmcnt.
static __device__ __forceinline__ void bar_sync() {
    __builtin_amdgcn_sched_barrier(0);
    asm volatile("s_waitcnt lgkmcnt(0)" ::: "memory");
    __builtin_amdgcn_sched_barrier(0);
    __builtin_amdgcn_s_barrier();
    __builtin_amdgcn_sched_barrier(0);
}

// ---------------------------------------------------------------------------
// Kernel A: Y = X @ W^T + bias, split-bf16 output.
// R4: 512 threads / 8 waves (2 waves/SIMD) for latency hiding; wave grid
// 2x4 over the 128x128 tile (each wave owns 64x32). Numerics identical to R3.
// ---------------------------------------------------------------------------
template<int TERMS, int MODE>
__launch_bounds__(512, 2)
__global__ void proj_kernel(const float* __restrict__ X, const float* __restrict__ W,
                            const float* __restrict__ bias,
                            u16* __restrict__ Yhi, u16* __restrict__ Ylo, float scale)
{
    __shared__ u16 xh[128][40], xl[128][40], wh[128][40], wl[128][40];
    const int t = threadIdx.x;
    const int lane = t & 63, wave = t >> 6;          // 8 waves
    const int lg = lane >> 4, lr = lane & 15;
    const int wr = (wave >> 2) * 64, wc = (wave & 3) * 32;
    const int m0 = blockIdx.x * 128, n0 = blockIdx.y * 128;

    f32x4 acc[4][2] = {};

    for (int k0 = 0; k0 < HD; k0 += 32) {
        // stage X and W tiles (128 x 32 f32 each): 2 float4 per thread each
        #pragma unroll
        for (int i = 0; i < 2; i++) {
            int idx = t + i * 512;
            int r = idx >> 3, c = (idx & 7) * 4;
            float4 v = *(const float4*)(X + (size_t)(m0 + r) * HD + k0 + c);
            u16 h0 = f2bf(v.x), h1 = f2bf(v.y), h2 = f2bf(v.z), h3 = f2bf(v.w);
            u16x4 hv; hv[0] = h0; hv[1] = h1; hv[2] = h2; hv[3] = h3;
            *(u16x4*)&xh[r][c] = hv;
            if (TERMS >= 2) {
                u16x4 lv;
                lv[0] = f2bf(v.x - bf2f(h0)); lv[1] = f2bf(v.y - bf2f(h1));
                lv[2] = f2bf(v.z - bf2f(h2)); lv[3] = f2bf(v.w - bf2f(h3));
                *(u16x4*)&xl[r][c] = lv;
            }
            float4 w = *(const float4*)(W + (size_t)(n0 + r) * HD + k0 + c);
            u16 g0 = f2bf(w.x), g1 = f2bf(w.y), g2 = f2bf(w.z), g3 = f2bf(w.w);
            u16x4 gv; gv[0] = g0; gv[1] = g1; gv[2] = g2; gv[3] = g3;
            *(u16x4*)&wh[r][c] = gv;
            if (TERMS >= 3) {
                u16x4 lv;
                lv[0] = f2bf(w.x - bf2f(g0)); lv[1] = f2bf(w.y - bf2f(g1));
                lv[2] = f2bf(w.z - bf2f(g2)); lv[3] = f2bf(w.w - bf2f(g3));
                *(u16x4*)&wl[r][c] = lv;
            }
        }
        __syncthreads();
        const int kk = lg * 8;
        s16x8 ah[4], al[4], bh[2], bl[2];
        #pragma unroll
        for (int f = 0; f < 4; f++) {
            ah[f] = ld8(&xh[wr + f * 16 + lr][kk]);
            if (TERMS >= 2) al[f] = ld8(&xl[wr + f * 16 + lr][kk]);
        }
        #pragma unroll
        for (int f = 0; f < 2; f++) {
            bh[f] = ld8(&wh[wc + f * 16 + lr][kk]);
            if (TERMS >= 3) bl[f] = ld8(&wl[wc + f * 16 + lr][kk]);
        }
        #pragma unroll
        for (int m = 0; m < 4; m++)
            #pragma unroll
            for (int n = 0; n < 2; n++) {
                acc[m][n] = mm16(ah[m], bh[n], acc[m][n]);
                if (TERMS >= 2) acc[m][n] = mm16(al[m], bh[n], acc[m][n]);
                if (TERMS >= 3) acc[m][n] = mm16(ah[m], bl[n], acc[m][n]);
            }
        __syncthreads();
    }

    float bv[2];
    #pragma unroll
    for (int n = 0; n < 2; n++) bv[n] = bias[n0 + wc + n * 16 + lr];

    #pragma unroll
    for (int m = 0; m < 4; m++)
        #pragma unroll
        for (int n = 0; n < 2; n++) {
            int col = n0 + wc + n * 16 + lr;
            int h = col >> 6, d = col & 63;
            #pragma unroll
            for (int j = 0; j < 4; j++) {
                int row = m0 + wr + m * 16 + lg * 4 + j;
                int b = row >> 12, nn = row & (NSEQ - 1);
                float y = (acc[m][n][j] + bv[n]) * scale;
                u16 hi = f2bf(y);
                if (MODE == 0) {
                    size_t o = (((size_t)(b * NH + h) * NSEQ) + nn) * DKH + d;
                    Yhi[o] = hi;
                    Ylo[o] = f2bf(y - bf2f(hi));
                } else {
                    size_t o = ((size_t)(b * NH + h) * DKH + d) * (size_t)NSEQ + nn;
                    Yhi[o] = hi;
                }
            }
        }
}

// ---------------------------------------------------------------------------
// XCD-aware swizzle: each XCD owns bh pair {2r, 2r+1} -> K/V L2-resident.
// ---------------------------------------------------------------------------
static __device__ __forceinline__ void swz_bh_q(int& bh, int& qblk) {
    int f = blockIdx.x + 32 * blockIdx.y;
    int r = f & 7, q = f >> 3;
    bh = 2 * r + (q >> 5);
    qblk = q & 31;
}

// ---------------------------------------------------------------------------
// Kernel C (fused): UNCHANGED from R3 (attribution control).
// ---------------------------------------------------------------------------
#define NT (NSEQ / 64)

__launch_bounds__(256, 2)
__global__ void attn_kernel(const u16* __restrict__ Qh, const u16* __restrict__ Ql,
                            const u16* __restrict__ Kh, const u16* __restrict__ Kl,
                            const u16* __restrict__ Vt,
                            float* __restrict__ attn, u16* __restrict__ ctx)
{
    __shared__ u16 kh[2][64][72], kl[2][64][72], vt[2][64][72];
    __shared__ u16 plds[4][32][72];
    const int t = threadIdx.x, lane = t & 63, wave = t >> 6;
    const int lg = lane >> 4, lr = lane & 15;
    int bh, qblk; swz_bh_q(bh, qblk);
    const int q0 = qblk * 128 + wave * 32;
    const size_t nbase = (size_t)bh * NSEQ;

    const int sr = t >> 3;
    const int sc = (t & 7) * 8;
    const u16* gK  = Kh + nbase * DKH + (size_t)sr * DKH + sc;
    const u16* gKl = Kl + nbase * DKH + (size_t)sr * DKH + sc;
    const u16* gV  = Vt + ((size_t)bh * DKH + sr) * NSEQ + sc;

    s16x8 qh[2][2], ql[2][2];
    #pragma unroll
    for (int qi = 0; qi < 2; qi++)
        #pragma unroll
        for (int ds = 0; ds < 2; ds++) {
            size_t o = (nbase + q0 + qi * 16 + lr) * DKH + ds * 32 + lg * 8;
            qh[qi][ds] = ld8(Qh + o);
            ql[qi][ds] = ld8(Ql + o);
        }

    // ================= phase 1: l[row] = sum_k exp(s1) =================
    float sums[2][4] = {};
    {
        *(u16x8*)&kh[0][sr][sc]      = *(const u16x8*)(gK);
        *(u16x8*)&kh[0][sr + 32][sc] = *(const u16x8*)(gK + (size_t)32 * DKH);
        bar_sync();
        for (int tt = 0; tt < NT; tt++) {
            const int cur = tt & 1, nxt = cur ^ 1;
            u16x8 pk0, pk1;
            if (tt + 1 < NT) {
                pk0 = *(const u16x8*)(gK + (size_t)(tt * 64 + 64) * DKH);
                pk1 = *(const u16x8*)(gK + (size_t)(tt * 64 + 96) * DKH);
            }
            f32x4 S[2][4] = {};
            __builtin_amdgcn_s_setprio(1);
            #pragma unroll
            for (int ds = 0; ds < 2; ds++) {
                s16x8 bf[4];
                #pragma unroll
                for (int kf = 0; kf < 4; kf++)
                    bf[kf] = ld8(&kh[cur][kf * 16 + lr][ds * 32 + lg * 8]);
                #pragma unroll
                for (int qi = 0; qi < 2; qi++)
                    #pragma unroll
                    for (int kf = 0; kf < 4; kf++)
                        S[qi][kf] = mm16(qh[qi][ds], bf[kf], S[qi][kf]);
            }
            __builtin_amdgcn_s_setprio(0);
            #pragma unroll
            for (int qi = 0; qi < 2; qi++)
                #pragma unroll
                for (int kf = 0; kf < 4; kf++)
                    #pragma unroll
                    for (int j = 0; j < 4; j++)
                        sums[qi][j] += __builtin_amdgcn_exp2f(S[qi][kf][j] * L2E);
            if (tt + 1 < NT) {
                *(u16x8*)&kh[nxt][sr][sc]      = pk0;
                *(u16x8*)&kh[nxt][sr + 32][sc] = pk1;
            }
            bar_sync();
        }
    }
    #pragma unroll
    for (int m = 1; m < 16; m <<= 1)
        #pragma unroll
        for (int qi = 0; qi < 2; qi++)
            #pragma unroll
            for (int j = 0; j < 4; j++)
                sums[qi][j] += __shfl_xor(sums[qi][j], m, 64);

    float lrl[2][4];
    size_t arow[2][4];
    #pragma unroll
    for (int qi = 0; qi < 2; qi++)
        #pragma unroll
        for (int j = 0; j < 4; j++) {
            int row = q0 + qi * 16 + lg * 4 + j;
            lrl[qi][j] = -__builtin_amdgcn_logf(sums[qi][j]);   // -log2(l)
            arow[qi][j] = (nbase + row) * (size_t)NSEQ + lr;
        }

    // ================= phase 2: attn + PV =================
    #pragma unroll
    for (int i = 0; i < 2; i++) {
        int r = sr + i * 32;
        *(u16x8*)&kh[0][r][sc] = *(const u16x8*)(gK  + (size_t)(i * 32) * DKH);
        *(u16x8*)&kl[0][r][sc] = *(const u16x8*)(gKl + (size_t)(i * 32) * DKH);
        *(u16x8*)&vt[0][r][sc] = *(const u16x8*)(gV  + (size_t)(i * 32) * NSEQ);
    }
    bar_sync();

    f32x4 O[2][4] = {};
    for (int tt = 0; tt < NT; tt++) {
        const int cur = tt & 1, nxt = cur ^ 1;
        const int k0 = tt * 64;

        u16x8 pk[2], pkl[2], pv[2];
        if (tt + 1 < NT) {
            #pragma unroll
            for (int i = 0; i < 2; i++) {
                size_t ko = (size_t)(k0 + 64 + i * 32);
                pk[i]  = *(const u16x8*)(gK  + ko * DKH);
                pkl[i] = *(const u16x8*)(gKl + ko * DKH);
                pv[i]  = *(const u16x8*)(gV  + (size_t)(i * 32) * NSEQ + k0 + 64);
            }
        }

        f32x4 S[2][4] = {};
        __builtin_amdgcn_s_setprio(1);
        #pragma unroll
        for (int ds = 0; ds < 2; ds++) {
            s16x8 bkh[4], bkl[4];
            #pragma unroll
            for (int kf = 0; kf < 4; kf++) {
                bkh[kf] = ld8(&kh[cur][kf * 16 + lr][ds * 32 + lg * 8]);
                bkl[kf] = ld8(&kl[cur][kf * 16 + lr][ds * 32 + lg * 8]);
            }
            #pragma unroll
            for (int qi = 0; qi < 2; qi++)
                #pragma unroll
                for (int kf = 0; kf < 4; kf++) {
                    S[qi][kf] = mm16(qh[qi][ds], bkh[kf], S[qi][kf]);
                    S[qi][kf] = mm16(ql[qi][ds], bkh[kf], S[qi][kf]);
                    S[qi][kf] = mm16(qh[qi][ds], bkl[kf], S[qi][kf]);
                }
        }
        __builtin_amdgcn_s_setprio(0);

        #pragma unroll
        for (int qi = 0; qi < 2; qi++)
            #pragma unroll
            for (int kf = 0; kf < 4; kf++)
                #pragma unroll
                for (int j = 0; j < 4; j++) {
                    float p = __builtin_amdgcn_exp2f(fmaf(S[qi][kf][j], L2E, lrl[qi][j]));
                    __builtin_nontemporal_store(p, &attn[arow[qi][j] + k0 + kf * 16]);
                    plds[wave][qi * 16 + lg * 4 + j][kf * 16 + lr] = f2bf(p);
                }

        __builtin_amdgcn_wave_barrier();   // plds is wave-private

        __builtin_amdgcn_s_setprio(1);
        #pragma unroll
        for (int ks = 0; ks < 2; ks++) {
            s16x8 pa[2], vb[4];
            #pragma unroll
            for (int qi = 0; qi < 2; qi++)
                pa[qi] = ld8(&plds[wave][qi * 16 + lr][ks * 32 + lg * 8]);
            #pragma unroll
            for (int df = 0; df < 4; df++)
                vb[df] = ld8(&vt[cur][df * 16 + lr][ks * 32 + lg * 8]);
            #pragma unroll
            for (int qi = 0; qi < 2; qi++)
                #pragma unroll
                for (int df = 0; df < 4; df++)
                    O[qi][df] = mm16(pa[qi], vb[df], O[qi][df]);
        }
        __builtin_amdgcn_s_setprio(0);

        if (tt + 1 < NT) {
            #pragma unroll
            for (int i = 0; i < 2; i++) {
                int r = sr + i * 32;
                *(u16x8*)&kh[nxt][r][sc] = pk[i];
                *(u16x8*)&kl[nxt][r][sc] = pkl[i];
                *(u16x8*)&vt[nxt][r][sc] = pv[i];
            }
        }
        bar_sync();
    }

    const int b = bh >> 3, h = bh & 7;
    #pragma unroll
    for (int qi = 0; qi < 2; qi++)
        #pragma unroll
        for (int df = 0; df < 4; df++)
            #pragma unroll
            for (int j = 0; j < 4; j++) {
                int n = q0 + qi * 16 + lg * 4 + j;
                int col = h * 64 + df * 16 + lr;
                ctx[((size_t)b * NSEQ + n) * HD + col] = f2bf(O[qi][df][j]);
            }
}

// ---------------------------------------------------------------------------
// Kernel D: out = ctx @ Wo^T + bo.  R4: 512 threads / 8 waves (2 waves/SIMD).
// ---------------------------------------------------------------------------
__launch_bounds__(512, 2)
__global__ void outproj_kernel(const u16* __restrict__ Xc, const float* __restrict__ W,
                               const float* __restrict__ bias, float* __restrict__ out)
{
    __shared__ u16 xh[128][72], wh[128][72];
    const int t = threadIdx.x, lane = t & 63, wave = t >> 6;   // 8 waves
    const int lg = lane >> 4, lr = lane & 15;
    const int wr = (wave >> 2) * 64, wc = (wave & 3) * 32;
    const int m0 = blockIdx.x * 128, n0 = blockIdx.y * 128;

    f32x4 acc[4][2] = {};
    for (int k0 = 0; k0 < HD; k0 += 64) {
        #pragma unroll
        for (int i = 0; i < 2; i++) {
            int idx = t + i * 512;
            int r = idx >> 3, c = (idx & 7) * 8;
            *(u16x8*)&xh[r][c] = *(const u16x8*)(Xc + (size_t)(m0 + r) * HD + k0 + c);
        }
        #pragma unroll
        for (int i = 0; i < 4; i++) {
            int idx = t + i * 512;
            int r = idx >> 4, c = (idx & 15) * 4;
            float4 v = *(const float4*)(W + (size_t)(n0 + r) * HD + k0 + c);
            u16x4 gv; gv[0] = f2bf(v.x); gv[1] = f2bf(v.y); gv[2] = f2bf(v.z); gv[3] = f2bf(v.w);
            *(u16x4*)&wh[r][c] = gv;
        }
        __syncthreads();
        #pragma unroll
        for (int ks = 0; ks < 2; ks++) {
            s16x8 af[4], bf[2];
            int kk = ks * 32 + lg * 8;
            #pragma unroll
            for (int f = 0; f < 4; f++) af[f] = ld8(&xh[wr + f * 16 + lr][kk]);
            #pragma unroll
            for (int f = 0; f < 2; f++) bf[f] = ld8(&wh[wc + f * 16 + lr][kk]);
            #pragma unroll
            for (int m = 0; m < 4; m++)
                #pragma unroll
                for (int n = 0; n < 2; n++)
                    acc[m][n] = mm16(af[m], bf[n], acc[m][n]);
        }
        __syncthreads();
    }
    #pragma unroll
    for (int m = 0; m < 4; m++)
        #pragma unroll
        for (int n = 0; n < 2; n++) {
            int col = n0 + wc + n * 16 + lr;
            float bv = bias[col];
            #pragma unroll
            for (int j = 0; j < 4; j++) {
                int row = m0 + wr + m * 16 + lg * 4 + j;
                out[(size_t)row * HD + col] = acc[m][n][j] + bv;
            }
        }
}

// ---------------------------------------------------------------------------
extern "C" void kernel_launch(void* const* d_in, const int* in_sizes, int n_in,
                              void* d_out, int out_size, void* d_ws, size_t ws_size,
                              hipStream_t stream)
{
    const float* query = (const float*)d_in[0];
    const float* key   = (const float*)d_in[1];
    const float* value = (const float*)d_in[2];
    const float* Wq = (const float*)d_in[3];
    const float* bq = (const float*)d_in[4];
    const float* Wk = (const float*)d_in[5];
    const float* bk = (const float*)d_in[6];
    const float* Wv = (const float*)d_in[7];
    const float* bv = (const float*)d_in[8];
    const float* Wo = (const float*)d_in[9];
    const float* bo = (const float*)d_in[10];

    float* out  = (float*)d_out;
    float* attn = out + (size_t)NB * NSEQ * HD;

    const size_t E = (size_t)NB * NH * NSEQ * DKH;
    u16* qhi = (u16*)d_ws;
    u16* qlo = qhi + E;
    u16* khi = qlo + E;
    u16* klo = khi + E;
    u16* vt  = klo + E;
    u16* ctx = vt + E;

    dim3 gp(64, 4), bp(512);
    proj_kernel<3, 0><<<gp, bp, 0, stream>>>(query, Wq, bq, qhi, qlo, 0.125f);
    proj_kernel<3, 0><<<gp, bp, 0, stream>>>(key,   Wk, bk, khi, klo, 1.0f);
    proj_kernel<1, 1><<<gp, bp, 0, stream>>>(value, Wv, bv, vt, (u16*)nullptr, 1.0f);
    attn_kernel<<<dim3(32, 16), dim3(256), 0, stream>>>(qhi, qlo, khi, klo, vt, attn, ctx);
    outproj_kernel<<<gp, bp, 0, stream>>>(ctx, Wo, bo, out);
}

// Round 5
// 502.330 us; speedup vs baseline: 1.0989x; 1.0562x over previous
//
#include <hip/hip_runtime.h>
#include <hip/hip_bf16.h>

#define NB   2
#define NH   8
#define NSEQ 4096
#define DKH  64
#define HD   512

typedef unsigned short u16;
typedef unsigned int   u32;
typedef short s16x8 __attribute__((ext_vector_type(8)));
typedef u16   u16x8 __attribute__((ext_vector_type(8)));
typedef u16   u16x4 __attribute__((ext_vector_type(4)));
typedef u32   u32x2 __attribute__((ext_vector_type(2)));
typedef float f32x4 __attribute__((ext_vector_type(4)));

#define L2E 1.4426950408889634f

static __device__ __forceinline__ u16 f2bf(float f) {
    u32 u = __builtin_bit_cast(u32, f);
    u32 r = (u + 0x7fffu + ((u >> 16) & 1u)) >> 16;
    return (u16)r;
}
static __device__ __forceinline__ float bf2f(u16 h) {
    return __builtin_bit_cast(float, (u32)h << 16);
}
static __device__ __forceinline__ f32x4 mm16(s16x8 a, s16x8 b, f32x4 c) {
    return __builtin_amdgcn_mfma_f32_16x16x32_bf16(a, b, c, 0, 0, 0);
}
static __device__ __forceinline__ s16x8 ld8(const u16* p) {
    return __builtin_bit_cast(s16x8, *(const u16x8*)p);
}
// Raw barrier: LDS-only ordering, does NOT drain vmcnt.
static __device__ __forceinline__ void bar_sync() {
    __builtin_amdgcn_sched_barrier(0);
    asm volatile("s_waitcnt lgkmcnt(0)" ::: "memory");
    __builtin_amdgcn_sched_barrier(0);
    __builtin_amdgcn_s_barrier();
    __builtin_amdgcn_sched_barrier(0);
}

// ---------------------------------------------------------------------------
// Kernel A: Y = X @ W^T + bias, split-bf16 output.  (unchanged from R4)
// ---------------------------------------------------------------------------
template<int TERMS, int MODE>
__launch_bounds__(512, 2)
__global__ void proj_kernel(const float* __restrict__ X, const float* __restrict__ W,
                            const float* __restrict__ bias,
                            u16* __restrict__ Yhi, u16* __restrict__ Ylo, float scale)
{
    __shared__ u16 xh[128][40], xl[128][40], wh[128][40], wl[128][40];
    const int t = threadIdx.x;
    const int lane = t & 63, wave = t >> 6;          // 8 waves
    const int lg = lane >> 4, lr = lane & 15;
    const int wr = (wave >> 2) * 64, wc = (wave & 3) * 32;
    const int m0 = blockIdx.x * 128, n0 = blockIdx.y * 128;

    f32x4 acc[4][2] = {};

    for (int k0 = 0; k0 < HD; k0 += 32) {
        #pragma unroll
        for (int i = 0; i < 2; i++) {
            int idx = t + i * 512;
            int r = idx >> 3, c = (idx & 7) * 4;
            float4 v = *(const float4*)(X + (size_t)(m0 + r) * HD + k0 + c);
            u16 h0 = f2bf(v.x), h1 = f2bf(v.y), h2 = f2bf(v.z), h3 = f2bf(v.w);
            u16x4 hv; hv[0] = h0; hv[1] = h1; hv[2] = h2; hv[3] = h3;
            *(u16x4*)&xh[r][c] = hv;
            if (TERMS >= 2) {
                u16x4 lv;
                lv[0] = f2bf(v.x - bf2f(h0)); lv[1] = f2bf(v.y - bf2f(h1));
                lv[2] = f2bf(v.z - bf2f(h2)); lv[3] = f2bf(v.w - bf2f(h3));
                *(u16x4*)&xl[r][c] = lv;
            }
            float4 w = *(const float4*)(W + (size_t)(n0 + r) * HD + k0 + c);
            u16 g0 = f2bf(w.x), g1 = f2bf(w.y), g2 = f2bf(w.z), g3 = f2bf(w.w);
            u16x4 gv; gv[0] = g0; gv[1] = g1; gv[2] = g2; gv[3] = g3;
            *(u16x4*)&wh[r][c] = gv;
            if (TERMS >= 3) {
                u16x4 lv;
                lv[0] = f2bf(w.x - bf2f(g0)); lv[1] = f2bf(w.y - bf2f(g1));
                lv[2] = f2bf(w.z - bf2f(g2)); lv[3] = f2bf(w.w - bf2f(g3));
                *(u16x4*)&wl[r][c] = lv;
            }
        }
        __syncthreads();
        const int kk = lg * 8;
        s16x8 ah[4], al[4], bh[2], bl[2];
        #pragma unroll
        for (int f = 0; f < 4; f++) {
            ah[f] = ld8(&xh[wr + f * 16 + lr][kk]);
            if (TERMS >= 2) al[f] = ld8(&xl[wr + f * 16 + lr][kk]);
        }
        #pragma unroll
        for (int f = 0; f < 2; f++) {
            bh[f] = ld8(&wh[wc + f * 16 + lr][kk]);
            if (TERMS >= 3) bl[f] = ld8(&wl[wc + f * 16 + lr][kk]);
        }
        #pragma unroll
        for (int m = 0; m < 4; m++)
            #pragma unroll
            for (int n = 0; n < 2; n++) {
                acc[m][n] = mm16(ah[m], bh[n], acc[m][n]);
                if (TERMS >= 2) acc[m][n] = mm16(al[m], bh[n], acc[m][n]);
                if (TERMS >= 3) acc[m][n] = mm16(ah[m], bl[n], acc[m][n]);
            }
        __syncthreads();
    }

    float bv[2];
    #pragma unroll
    for (int n = 0; n < 2; n++) bv[n] = bias[n0 + wc + n * 16 + lr];

    #pragma unroll
    for (int m = 0; m < 4; m++)
        #pragma unroll
        for (int n = 0; n < 2; n++) {
            int col = n0 + wc + n * 16 + lr;
            int h = col >> 6, d = col & 63;
            #pragma unroll
            for (int j = 0; j < 4; j++) {
                int row = m0 + wr + m * 16 + lg * 4 + j;
                int b = row >> 12, nn = row & (NSEQ - 1);
                float y = (acc[m][n][j] + bv[n]) * scale;
                u16 hi = f2bf(y);
                if (MODE == 0) {
                    size_t o = (((size_t)(b * NH + h) * NSEQ) + nn) * DKH + d;
                    Yhi[o] = hi;
                    Ylo[o] = f2bf(y - bf2f(hi));
                } else {
                    size_t o = ((size_t)(b * NH + h) * DKH + d) * (size_t)NSEQ + nn;
                    Yhi[o] = hi;
                }
            }
        }
}

// ---------------------------------------------------------------------------
// XCD-aware swizzle: each XCD owns bh pair {2r, 2r+1} -> K/V L2-resident.
// ---------------------------------------------------------------------------
static __device__ __forceinline__ void swz_bh_q(int& bh, int& qblk) {
    int f = blockIdx.x + 32 * blockIdx.y;
    int r = f & 7, q = f >> 3;
    bh = 2 * r + (q >> 5);
    qblk = q & 31;
}

// ---------------------------------------------------------------------------
// Kernel C (fused). R5: SWAPPED score MFMA — S = mfma(K_frag, Q_frag) gives
// C layout [k][q]: each thread holds 4 CONSECUTIVE k for one q-row
// (q = qi*16+lr, k = kf*16+lg*4+j).  attn stores become dwordx4 from regs
// (8/tile vs 32 scattered dwords, nt dropped -> L2 write-combining);
// plds writes become 8 x ds_write_b64 (packed bf16x4).  PV unchanged.
// ---------------------------------------------------------------------------
#define NT (NSEQ / 64)

__launch_bounds__(256, 2)
__global__ void attn_kernel(const u16* __restrict__ Qh, const u16* __restrict__ Ql,
                            const u16* __restrict__ Kh, const u16* __restrict__ Kl,
                            const u16* __restrict__ Vt,
                            float* __restrict__ attn, u16* __restrict__ ctx)
{
    __shared__ u16 kh[2][64][72], kl[2][64][72], vt[2][64][72];
    __shared__ u16 plds[4][32][72];
    const int t = threadIdx.x, lane = t & 63, wave = t >> 6;
    const int lg = lane >> 4, lr = lane & 15;
    int bh, qblk; swz_bh_q(bh, qblk);
    const int q0 = qblk * 128 + wave * 32;
    const size_t nbase = (size_t)bh * NSEQ;

    const int sr = t >> 3;
    const int sc = (t & 7) * 8;
    const u16* gK  = Kh + nbase * DKH + (size_t)sr * DKH + sc;
    const u16* gKl = Kl + nbase * DKH + (size_t)sr * DKH + sc;
    const u16* gV  = Vt + ((size_t)bh * DKH + sr) * NSEQ + sc;

    s16x8 qh[2][2], ql[2][2];
    #pragma unroll
    for (int qi = 0; qi < 2; qi++)
        #pragma unroll
        for (int ds = 0; ds < 2; ds++) {
            size_t o = (nbase + q0 + qi * 16 + lr) * DKH + ds * 32 + lg * 8;
            qh[qi][ds] = ld8(Qh + o);
            ql[qi][ds] = ld8(Ql + o);
        }

    // ================= phase 1: l[q] = sum_k exp(s1), swapped layout ======
    float sums[2] = {0.f, 0.f};
    {
        *(u16x8*)&kh[0][sr][sc]      = *(const u16x8*)(gK);
        *(u16x8*)&kh[0][sr + 32][sc] = *(const u16x8*)(gK + (size_t)32 * DKH);
        bar_sync();
        for (int tt = 0; tt < NT; tt++) {
            const int cur = tt & 1, nxt = cur ^ 1;
            u16x8 pk0, pk1;
            if (tt + 1 < NT) {
                pk0 = *(const u16x8*)(gK + (size_t)(tt * 64 + 64) * DKH);
                pk1 = *(const u16x8*)(gK + (size_t)(tt * 64 + 96) * DKH);
            }
            f32x4 S[2][4] = {};
            __builtin_amdgcn_s_setprio(1);
            #pragma unroll
            for (int ds = 0; ds < 2; ds++) {
                s16x8 bf[4];
                #pragma unroll
                for (int kf = 0; kf < 4; kf++)
                    bf[kf] = ld8(&kh[cur][kf * 16 + lr][ds * 32 + lg * 8]);
                #pragma unroll
                for (int qi = 0; qi < 2; qi++)
                    #pragma unroll
                    for (int kf = 0; kf < 4; kf++)
                        S[qi][kf] = mm16(bf[kf], qh[qi][ds], S[qi][kf]);
            }
            __builtin_amdgcn_s_setprio(0);
            #pragma unroll
            for (int qi = 0; qi < 2; qi++)
                #pragma unroll
                for (int kf = 0; kf < 4; kf++)
                    #pragma unroll
                    for (int j = 0; j < 4; j++)
                        sums[qi] += __builtin_amdgcn_exp2f(S[qi][kf][j] * L2E);
            if (tt + 1 < NT) {
                *(u16x8*)&kh[nxt][sr][sc]      = pk0;
                *(u16x8*)&kh[nxt][sr + 32][sc] = pk1;
            }
            bar_sync();
        }
    }
    // reduce across the 4 lg-groups (lanes sharing lr)
    #pragma unroll
    for (int qi = 0; qi < 2; qi++) {
        sums[qi] += __shfl_xor(sums[qi], 16, 64);
        sums[qi] += __shfl_xor(sums[qi], 32, 64);
    }

    float lrl[2];
    float* aptr[2];
    #pragma unroll
    for (int qi = 0; qi < 2; qi++) {
        lrl[qi] = -__builtin_amdgcn_logf(sums[qi]);   // -log2(l)
        aptr[qi] = attn + (nbase + q0 + qi * 16 + lr) * (size_t)NSEQ + lg * 4;
    }

    // ================= phase 2: attn + PV =================
    #pragma unroll
    for (int i = 0; i < 2; i++) {
        int r = sr + i * 32;
        *(u16x8*)&kh[0][r][sc] = *(const u16x8*)(gK  + (size_t)(i * 32) * DKH);
        *(u16x8*)&kl[0][r][sc] = *(const u16x8*)(gKl + (size_t)(i * 32) * DKH);
        *(u16x8*)&vt[0][r][sc] = *(const u16x8*)(gV  + (size_t)(i * 32) * NSEQ);
    }
    bar_sync();

    f32x4 O[2][4] = {};
    for (int tt = 0; tt < NT; tt++) {
        const int cur = tt & 1, nxt = cur ^ 1;
        const int k0 = tt * 64;

        u16x8 pk[2], pkl[2], pv[2];
        if (tt + 1 < NT) {
            #pragma unroll
            for (int i = 0; i < 2; i++) {
                size_t ko = (size_t)(k0 + 64 + i * 32);
                pk[i]  = *(const u16x8*)(gK  + ko * DKH);
                pkl[i] = *(const u16x8*)(gKl + ko * DKH);
                pv[i]  = *(const u16x8*)(gV  + (size_t)(i * 32) * NSEQ + k0 + 64);
            }
        }

        f32x4 S[2][4] = {};   // [qi][kf][j]: q = q0+qi*16+lr, k = k0+kf*16+lg*4+j
        __builtin_amdgcn_s_setprio(1);
        #pragma unroll
        for (int ds = 0; ds < 2; ds++) {
            s16x8 bkh[4], bkl[4];
            #pragma unroll
            for (int kf = 0; kf < 4; kf++) {
                bkh[kf] = ld8(&kh[cur][kf * 16 + lr][ds * 32 + lg * 8]);
                bkl[kf] = ld8(&kl[cur][kf * 16 + lr][ds * 32 + lg * 8]);
            }
            #pragma unroll
            for (int qi = 0; qi < 2; qi++)
                #pragma unroll
                for (int kf = 0; kf < 4; kf++) {
                    S[qi][kf] = mm16(bkh[kf], qh[qi][ds], S[qi][kf]);
                    S[qi][kf] = mm16(bkh[kf], ql[qi][ds], S[qi][kf]);
                    S[qi][kf] = mm16(bkl[kf], qh[qi][ds], S[qi][kf]);
                }
        }
        __builtin_amdgcn_s_setprio(0);

        // p = exp(s)/l; vectorized f32 store + packed bf16 into plds[q][k]
        #pragma unroll
        for (int qi = 0; qi < 2; qi++)
            #pragma unroll
            for (int kf = 0; kf < 4; kf++) {
                f32x4 p;
                #pragma unroll
                for (int j = 0; j < 4; j++)
                    p[j] = __builtin_amdgcn_exp2f(fmaf(S[qi][kf][j], L2E, lrl[qi]));
                *(f32x4*)(aptr[qi] + kf * 16) = p;
                u32x2 pk2;
                pk2[0] = (u32)f2bf(p[0]) | ((u32)f2bf(p[1]) << 16);
                pk2[1] = (u32)f2bf(p[2]) | ((u32)f2bf(p[3]) << 16);
                *(u32x2*)&plds[wave][qi * 16 + lr][kf * 16 + lg * 4] = pk2;
            }

        __builtin_amdgcn_wave_barrier();   // plds is wave-private

        __builtin_amdgcn_s_setprio(1);
        #pragma unroll
        for (int ks = 0; ks < 2; ks++) {
            s16x8 pa[2], vb[4];
            #pragma unroll
            for (int qi = 0; qi < 2; qi++)
                pa[qi] = ld8(&plds[wave][qi * 16 + lr][ks * 32 + lg * 8]);
            #pragma unroll
            for (int df = 0; df < 4; df++)
                vb[df] = ld8(&vt[cur][df * 16 + lr][ks * 32 + lg * 8]);
            #pragma unroll
            for (int qi = 0; qi < 2; qi++)
                #pragma unroll
                for (int df = 0; df < 4; df++)
                    O[qi][df] = mm16(pa[qi], vb[df], O[qi][df]);
        }
        __builtin_amdgcn_s_setprio(0);

        if (tt + 1 < NT) {
            #pragma unroll
            for (int i = 0; i < 2; i++) {
                int r = sr + i * 32;
                *(u16x8*)&kh[nxt][r][sc] = pk[i];
                *(u16x8*)&kl[nxt][r][sc] = pkl[i];
                *(u16x8*)&vt[nxt][r][sc] = pv[i];
            }
        }
        aptr[0] += 64;
        aptr[1] += 64;
        bar_sync();
    }

    const int b = bh >> 3, h = bh & 7;
    #pragma unroll
    for (int qi = 0; qi < 2; qi++)
        #pragma unroll
        for (int df = 0; df < 4; df++)
            #pragma unroll
            for (int j = 0; j < 4; j++) {
                int n = q0 + qi * 16 + lg * 4 + j;
                int col = h * 64 + df * 16 + lr;
                ctx[((size_t)b * NSEQ + n) * HD + col] = f2bf(O[qi][df][j]);
            }
}

// ---------------------------------------------------------------------------
// Kernel D: out = ctx @ Wo^T + bo.  (unchanged from R4)
// ---------------------------------------------------------------------------
__launch_bounds__(512, 2)
__global__ void outproj_kernel(const u16* __restrict__ Xc, const float* __restrict__ W,
                               const float* __restrict__ bias, float* __restrict__ out)
{
    __shared__ u16 xh[128][72], wh[128][72];
    const int t = threadIdx.x, lane = t & 63, wave = t >> 6;   // 8 waves
    const int lg = lane >> 4, lr = lane & 15;
    const int wr = (wave >> 2) * 64, wc = (wave & 3) * 32;
    const int m0 = blockIdx.x * 128, n0 = blockIdx.y * 128;

    f32x4 acc[4][2] = {};
    for (int k0 = 0; k0 < HD; k0 += 64) {
        #pragma unroll
        for (int i = 0; i < 2; i++) {
            int idx = t + i * 512;
            int r = idx >> 3, c = (idx & 7) * 8;
            *(u16x8*)&xh[r][c] = *(const u16x8*)(Xc + (size_t)(m0 + r) * HD + k0 + c);
        }
        #pragma unroll
        for (int i = 0; i < 4; i++) {
            int idx = t + i * 512;
            int r = idx >> 4, c = (idx & 15) * 4;
            float4 v = *(const float4*)(W + (size_t)(n0 + r) * HD + k0 + c);
            u16x4 gv; gv[0] = f2bf(v.x); gv[1] = f2bf(v.y); gv[2] = f2bf(v.z); gv[3] = f2bf(v.w);
            *(u16x4*)&wh[r][c] = gv;
        }
        __syncthreads();
        #pragma unroll
        for (int ks = 0; ks < 2; ks++) {
            s16x8 af[4], bf[2];
            int kk = ks * 32 + lg * 8;
            #pragma unroll
            for (int f = 0; f < 4; f++) af[f] = ld8(&xh[wr + f * 16 + lr][kk]);
            #pragma unroll
            for (int f = 0; f < 2; f++) bf[f] = ld8(&wh[wc + f * 16 + lr][kk]);
            #pragma unroll
            for (int m = 0; m < 4; m++)
                #pragma unroll
                for (int n = 0; n < 2; n++)
                    acc[m][n] = mm16(af[m], bf[n], acc[m][n]);
        }
        __syncthreads();
    }
    #pragma unroll
    for (int m = 0; m < 4; m++)
        #pragma unroll
        for (int n = 0; n < 2; n++) {
            int col = n0 + wc + n * 16 + lr;
            float bv = bias[col];
            #pragma unroll
            for (int j = 0; j < 4; j++) {
                int row = m0 + wr + m * 16 + lg * 4 + j;
                out[(size_t)row * HD + col] = acc[m][n][j] + bv;
            }
        }
}

// ---------------------------------------------------------------------------
extern "C" void kernel_launch(void* const* d_in, const int* in_sizes, int n_in,
                              void* d_out, int out_size, void* d_ws, size_t ws_size,
                              hipStream_t stream)
{
    const float* query = (const float*)d_in[0];
    const float* key   = (const float*)d_in[1];
    const float* value = (const float*)d_in[2];
    const float* Wq = (const float*)d_in[3];
    const float* bq = (const float*)d_in[4];
    const float* Wk = (const float*)d_in[5];
    const float* bk = (const float*)d_in[6];
    const float* Wv = (const float*)d_in[7];
    const float* bv = (const float*)d_in[8];
    const float* Wo = (const float*)d_in[9];
    const float* bo = (const float*)d_in[10];

    float* out  = (float*)d_out;
    float* attn = out + (size_t)NB * NSEQ * HD;

    const size_t E = (size_t)NB * NH * NSEQ * DKH;
    u16* qhi = (u16*)d_ws;
    u16* qlo = qhi + E;
    u16* khi = qlo + E;
    u16* klo = khi + E;
    u16* vt  = klo + E;
    u16* ctx = vt + E;

    dim3 gp(64, 4), bp(512);
    proj_kernel<3, 0><<<gp, bp, 0, stream>>>(query, Wq, bq, qhi, qlo, 0.125f);
    proj_kernel<3, 0><<<gp, bp, 0, stream>>>(key,   Wk, bk, khi, klo, 1.0f);
    proj_kernel<1, 1><<<gp, bp, 0, stream>>>(value, Wv, bv, vt, (u16*)nullptr, 1.0f);
    attn_kernel<<<dim3(32, 16), dim3(256), 0, stream>>>(qhi, qlo, khi, klo, vt, attn, ctx);
    outproj_kernel<<<gp, bp, 0, stream>>>(ctx, Wo, bo, out);
}